// Round 10
// baseline (364.135 us; speedup 1.0000x reference)
//
#include <hip/hip_runtime.h>

typedef unsigned short ushort_t;
typedef unsigned long long u64_t;
typedef __attribute__((ext_vector_type(8))) short short8;
typedef __attribute__((ext_vector_type(4))) float float4v;

__device__ inline float b2f(ushort_t u) {
    unsigned x = ((unsigned)u) << 16;
    return __builtin_bit_cast(float, x);
}
__device__ inline ushort_t f2b(float f) {
    unsigned x = __builtin_bit_cast(unsigned, f);
    unsigned r = (x + 0x7fffu + ((x >> 16) & 1u)) >> 16;
    return (ushort_t)r;
}

// Wave-uniform int64-vs-int32 edge_index detection: load the int2 pair at
// edge slot e (valid bytes in BOTH layouts); int64-little-endian => odd word
// is always 0. Any nonzero odd word in the wave => int32.
__device__ inline void load_edge(const int* __restrict__ ei, int e, int E,
                                 int& s, int& d) {
    int ec = min(e, E - 1);
    int2 c64 = ((const int2*)ei)[ec];
    unsigned long long m = __ballot(c64.y != 0);
    if (m != 0ull) {  // int32 layout
        s = ei[ec];
        d = ei[(size_t)E + ec];
    } else {          // int64 layout
        s = c64.x;
        d = ((const int2*)ei)[(size_t)E + ec].x;
    }
}

// ---------------- mega kernel: count (atomic CSR degree+rank) + casts ----------------

__global__ __launch_bounds__(256) void k_mega(const int* __restrict__ ei,
                                              const float* __restrict__ w,
                                              const float* __restrict__ x,
                                              const float* __restrict__ W1,
                                              const float* __restrict__ W2,
                                              u64_t* packed, int* __restrict__ rank,
                                              ushort_t* __restrict__ xb,
                                              ushort_t* __restrict__ W1b,
                                              ushort_t* __restrict__ W2b,
                                              int E, int Nn, int gE, int gX) {
    int b = blockIdx.x;
    if (b < gE) {
        int e = b * 256 + threadIdx.x;
        int s, d;
        load_edge(ei, e, E, s, d);
        if (e < E) {
            if ((unsigned)s < (unsigned)Nn && (unsigned)d < (unsigned)Nn) {
                unsigned fx = (unsigned)(w[e] * 16777216.0f + 0.5f);
                u64_t old = atomicAdd(packed + d, (1ull << 32) | (u64_t)fx);
                rank[e] = (int)(old >> 32);
            } else {
                rank[e] = -1;
            }
        }
    } else if (b < gE + gX) {
        int i = (b - gE) * 256 + threadIdx.x;  // float4 index
        if (i < Nn * 32) {
            float4v v = ((const float4v*)x)[i];
            ushort4 o;
            o.x = f2b(v[0]); o.y = f2b(v[1]); o.z = f2b(v[2]); o.w = f2b(v[3]);
            ((ushort4*)xb)[i] = o;
        }
    } else {
        int i = (b - gE - gX) * 256 + threadIdx.x;
        if (i < 32768) W1b[i] = f2b(W1[i]);
        else if (i < 65536) W2b[i - 32768] = f2b(W2[i - 32768]);
    }
}

__device__ inline int cnt_hi(const u64_t* packed, int i) {
    return ((const int*)packed)[2 * i + 1];  // little-endian high word
}

// ---------------- 3-phase multi-block exclusive scan over cnt_hi ----------------

__global__ __launch_bounds__(256) void k_scan_a(const u64_t* __restrict__ packed,
                                                int* __restrict__ bsum, int Nn) {
    int b = blockIdx.x, t = threadIdx.x;
    int base = b * 2048 + t * 8;
    int s = 0;
#pragma unroll
    for (int j = 0; j < 8; ++j) { int i = base + j; if (i < Nn) s += cnt_hi(packed, i); }
#pragma unroll
    for (int off = 1; off < 64; off <<= 1) s += __shfl_xor(s, off);
    __shared__ int wsum[4];
    if ((t & 63) == 0) wsum[t >> 6] = s;
    __syncthreads();
    if (t == 0) bsum[b] = wsum[0] + wsum[1] + wsum[2] + wsum[3];
}

__global__ void k_scan_b(const int* __restrict__ bsum, int* __restrict__ bbase,
                         int nb, int* __restrict__ offs, int Nn) {
    int t = threadIdx.x;
    int own = (t < nb) ? bsum[t] : 0;
    int v = own;
#pragma unroll
    for (int off = 1; off < 64; off <<= 1) {
        int u = __shfl_up(v, off);
        if (t >= off) v += u;
    }
    if (t < nb) bbase[t] = v - own;  // exclusive
    if (t == 63) offs[Nn] = v;       // grand total
}

__global__ __launch_bounds__(256) void k_scan_c(const u64_t* __restrict__ packed,
                                                const int* __restrict__ bbase,
                                                int* __restrict__ offs,
                                                float* __restrict__ dinv, int Nn) {
    int b = blockIdx.x, t = threadIdx.x;
    int base = b * 2048 + t * 8;
    u64_t pk[8];
    int v[8];
    int s = 0;
#pragma unroll
    for (int j = 0; j < 8; ++j) {
        int i = base + j;
        pk[j] = (i < Nn) ? packed[i] : 0ull;
        v[j] = (int)(pk[j] >> 32);
        s += v[j];
    }
    __shared__ int sd[256];
    sd[t] = s;
    __syncthreads();
    for (int off = 1; off < 256; off <<= 1) {
        int u = (t >= off) ? sd[t - off] : 0;
        __syncthreads();
        sd[t] += u;
        __syncthreads();
    }
    int pos = bbase[b] + sd[t] - s;
#pragma unroll
    for (int j = 0; j < 8; ++j) {
        int i = base + j;
        if (i < Nn) {
            offs[i] = pos; pos += v[j];
            float deg = 1.0f + (float)(unsigned)(pk[j] & 0xFFFFFFFFull) * (1.0f / 16777216.0f);
            dinv[i] = rsqrtf(deg);  // deg >= 1 (self loop)
        }
    }
}

// ---------------- scatter (atomic-free): edata[pos] = {src, bits(norm)} ----------------

__global__ void k_scatter(const int* __restrict__ ei, const float* __restrict__ w,
                          const float* __restrict__ dinv,
                          const int* __restrict__ offs,
                          const int* __restrict__ rank,
                          int2* __restrict__ edata, int E, int Nn) {
    int e = blockIdx.x * 256 + threadIdx.x;
    int s, d;
    load_edge(ei, e, E, s, d);  // full wave participates in ballot
    if (e >= E) return;
    int r = rank[e];
    if (r < 0) return;
    int pos = offs[d] + r;
    float nw = dinv[s] * w[e] * dinv[d];
    int2 p;
    p.x = s;
    p.y = __builtin_bit_cast(int, nw);
    edata[pos] = p;
}

// ---------------- quartered gather aggregation (XCD-L2-slab affinity) ----------------
// Feature dim split into 4 slabs of 32 dims (3.2 MB each < 4 MB per-XCD L2).
// blockIdx = g*8 + r: quarter q = r>>1 -> XCD pair {2q,2q+1} under the %8
// round-robin block->XCD mapping, so each XCD's L2 holds only its slab.
// Wave per (node, quarter): 4 edge-groups x 16 lanes x ushort2 -> 4 rows per
// VMEM instr; unroll x2 -> 8 edges in flight. Groups merged via shfl_xor(16,32).

template <bool SELF_SN>
__device__ inline void agg_quarter(const ushort_t* __restrict__ src,
                                   const int* __restrict__ offs,
                                   const int2* __restrict__ edata,
                                   const float* __restrict__ dinv,
                                   ushort_t* __restrict__ dst,
                                   int v, int q, int lane, int Nn) {
    int grp = lane >> 4, li = lane & 15;
    int doff = q * 32 + li * 2;
    float a0 = 0.f, a1 = 0.f;
    if (grp == 0) {  // self-loop in group 0 only
        float dv = dinv[v];
        float sn = dv * dv;
        ushort2 pq = *(const ushort2*)(src + (size_t)v * 128 + doff);
        a0 = b2f(pq.x) * sn; a1 = b2f(pq.y) * sn;
    }
    int s = offs[v], e = offs[v + 1];
    int i = s;
    for (; i + 7 < e; i += 8) {
        int2 e0 = edata[i + grp];
        int2 e1 = edata[i + 4 + grp];
        float n0 = __builtin_bit_cast(float, e0.y);
        float n1 = __builtin_bit_cast(float, e1.y);
        ushort2 q0 = *(const ushort2*)(src + (size_t)e0.x * 128 + doff);
        ushort2 q1 = *(const ushort2*)(src + (size_t)e1.x * 128 + doff);
        a0 += b2f(q0.x) * n0; a1 += b2f(q0.y) * n0;
        a0 += b2f(q1.x) * n1; a1 += b2f(q1.y) * n1;
    }
    for (; i < e; i += 4) {
        int idx = i + grp;
        int ic = min(idx, e - 1);
        int2 ed = edata[ic];
        float nw = (idx < e) ? __builtin_bit_cast(float, ed.y) : 0.f;
        ushort2 qq = *(const ushort2*)(src + (size_t)ed.x * 128 + doff);
        a0 += b2f(qq.x) * nw; a1 += b2f(qq.y) * nw;
    }
    a0 += __shfl_xor(a0, 16); a1 += __shfl_xor(a1, 16);
    a0 += __shfl_xor(a0, 32); a1 += __shfl_xor(a1, 32);
    if (lane < 16) {
        ushort2 o; o.x = f2b(a0); o.y = f2b(a1);
        *(ushort2*)(dst + (size_t)v * 128 + doff) = o;
    }
}

__global__ __launch_bounds__(256) void k_agg1q(const ushort_t* __restrict__ xb,
                                               const int* __restrict__ offs,
                                               const int2* __restrict__ edata,
                                               const float* __restrict__ dinv,
                                               ushort_t* __restrict__ ax, int Nn) {
    int r = blockIdx.x & 7, g = blockIdx.x >> 3;
    int q = r >> 1;
    int v = (g * 2 + (r & 1)) * 4 + (threadIdx.x >> 6);
    if (v >= Nn) return;
    agg_quarter<true>(xb, offs, edata, dinv, ax, v, q, threadIdx.x & 63, Nn);
}

__global__ __launch_bounds__(256) void k_agg2q(const ushort_t* __restrict__ h2,
                                               const int* __restrict__ offs,
                                               const int2* __restrict__ edata,
                                               const float* __restrict__ dinv,
                                               ushort_t* __restrict__ a2, int Nn) {
    int r = blockIdx.x & 7, g = blockIdx.x >> 3;
    int q = r >> 1;
    int v = (g * 2 + (r & 1)) * 4 + (threadIdx.x >> 6);
    if (v >= Nn) return;
    agg_quarter<true>(h2, offs, edata, dinv, a2, v, q, threadIdx.x & 63, Nn);
}

// ---------------- fused GEMM: h2 = relu(ax @ W1^T + b1) @ W2^T ----------------
// Block = 64 rows, 4 waves split the N dimension; W slices + a-frags register-
// prefetched. MFMA 16x16x32 bf16: A row=lane&15,k=quad*8+j; B col=lane&15,
// k=quad*8+j; D col=lane&15,row=quad*4+reg.

__global__ __launch_bounds__(256, 2) void k_gemm_fused(const ushort_t* __restrict__ ax,
                                                       const ushort_t* __restrict__ W1b,
                                                       const float* __restrict__ b1v,
                                                       const ushort_t* __restrict__ W2b,
                                                       ushort_t* __restrict__ h2, int Nn) {
    __shared__ ushort_t tile[64][264];  // 33792 B
    int tid = threadIdx.x, wid = tid >> 6, lane = tid & 63;
    int m = lane & 15, q = lane >> 4;
    int blk = blockIdx.x * 64;

    short8 wf[4][4];  // [nt][kt]
#pragma unroll
    for (int nt = 0; nt < 4; ++nt) {
        const ushort_t* wb = W1b + (size_t)(wid * 64 + nt * 16 + m) * 128 + q * 8;
#pragma unroll
        for (int kt = 0; kt < 4; ++kt) wf[nt][kt] = *(const short8*)(wb + kt * 32);
    }
    short8 af[4][4];  // [mi][kt]
#pragma unroll
    for (int mi = 0; mi < 4; ++mi) {
        int arow = blk + mi * 16 + m;
        bool rv = arow < Nn;
        const ushort_t* ab = ax + (size_t)arow * 128 + q * 8;
#pragma unroll
        for (int kt = 0; kt < 4; ++kt)
            af[mi][kt] = rv ? *(const short8*)(ab + kt * 32) : (short8)0;
    }

    float4v acc1[4][4];
#pragma unroll
    for (int mi = 0; mi < 4; ++mi)
#pragma unroll
        for (int nt = 0; nt < 4; ++nt) acc1[mi][nt] = (float4v){0.f, 0.f, 0.f, 0.f};

#pragma unroll
    for (int kt = 0; kt < 4; ++kt)
#pragma unroll
        for (int mi = 0; mi < 4; ++mi)
#pragma unroll
            for (int nt = 0; nt < 4; ++nt)
                acc1[mi][nt] = __builtin_amdgcn_mfma_f32_16x16x32_bf16(
                    af[mi][kt], wf[nt][kt], acc1[mi][nt], 0, 0, 0);

#pragma unroll
    for (int nt = 0; nt < 4; ++nt) {
        int col = wid * 64 + nt * 16 + m;
        float bb = b1v[col];
#pragma unroll
        for (int mi = 0; mi < 4; ++mi) {
#pragma unroll
            for (int r = 0; r < 4; ++r) {
                float v = acc1[mi][nt][r] + bb;
                v = v > 0.f ? v : 0.f;
                tile[mi * 16 + q * 4 + r][col] = f2b(v);
            }
        }
    }
    __syncthreads();

    short8 w2f[2][8];
#pragma unroll
    for (int n2 = 0; n2 < 2; ++n2) {
        const ushort_t* wb = W2b + (size_t)(wid * 32 + n2 * 16 + m) * 256 + q * 8;
#pragma unroll
        for (int kt = 0; kt < 8; ++kt) w2f[n2][kt] = *(const short8*)(wb + kt * 32);
    }

    float4v acc2[4][2];
#pragma unroll
    for (int mi = 0; mi < 4; ++mi)
#pragma unroll
        for (int n2 = 0; n2 < 2; ++n2) acc2[mi][n2] = (float4v){0.f, 0.f, 0.f, 0.f};

#pragma unroll
    for (int kt = 0; kt < 8; ++kt) {
#pragma unroll
        for (int mi = 0; mi < 4; ++mi) {
            short8 a2 = *(const short8*)&tile[mi * 16 + m][kt * 32 + q * 8];
#pragma unroll
            for (int n2 = 0; n2 < 2; ++n2)
                acc2[mi][n2] = __builtin_amdgcn_mfma_f32_16x16x32_bf16(
                    a2, w2f[n2][kt], acc2[mi][n2], 0, 0, 0);
        }
    }

#pragma unroll
    for (int mi = 0; mi < 4; ++mi) {
#pragma unroll
        for (int n2 = 0; n2 < 2; ++n2) {
            int col = wid * 32 + n2 * 16 + m;
#pragma unroll
            for (int r = 0; r < 4; ++r) {
                int row = blk + mi * 16 + q * 4 + r;
                if (row < Nn) h2[(size_t)row * 128 + col] = f2b(acc2[mi][n2][r]);
            }
        }
    }
}

// ---------------- bias + LayerNorm (a2 bf16 -> fp32 out), wave per node ----------------

__global__ __launch_bounds__(256) void k_ln(const ushort_t* __restrict__ a2,
                                            const float* __restrict__ b2v,
                                            const float* __restrict__ gv,
                                            const float* __restrict__ bev,
                                            float* __restrict__ out, int Nn) {
    int v = (blockIdx.x * blockDim.x + threadIdx.x) >> 6;
    int lane = threadIdx.x & 63;
    if (v >= Nn) return;
    int d0 = lane * 2;
    ushort2 p = ((const ushort2*)(a2 + (size_t)v * 128))[lane];
    float a0 = b2f(p.x) + b2v[d0];
    float a1 = b2f(p.y) + b2v[d0 + 1];
    float ssum = a0 + a1, ssq = a0 * a0 + a1 * a1;
#pragma unroll
    for (int off = 1; off < 64; off <<= 1) {
        ssum += __shfl_xor(ssum, off);
        ssq += __shfl_xor(ssq, off);
    }
    float mu = ssum * (1.0f / 128.0f);
    float var = ssq * (1.0f / 128.0f) - mu * mu;
    float r = rsqrtf(var + 1e-5f);
    float2 o;
    o.x = (a0 - mu) * r * gv[d0] + bev[d0];
    o.y = (a1 - mu) * r * gv[d0 + 1] + bev[d0 + 1];
    ((float2*)(out + (size_t)v * 128))[lane] = o;
}

// ---------------- launch ----------------

extern "C" void kernel_launch(void* const* d_in, const int* in_sizes, int n_in,
                              void* d_out, int out_size, void* d_ws, size_t ws_size,
                              hipStream_t stream) {
    const float* x   = (const float*)d_in[0];  // [N,128] f32
    const int*   ei  = (const int*)d_in[1];    // [2,E] int32/int64 (detected)
    const float* ew  = (const float*)d_in[2];  // [E] f32
    const float* W1  = (const float*)d_in[3];  // [256,128] f32
    const float* b1v = (const float*)d_in[4];  // [256]
    const float* W2  = (const float*)d_in[5];  // [128,256]
    const float* b2v = (const float*)d_in[6];  // [128]
    const float* gv  = (const float*)d_in[7];  // [128]
    const float* bev = (const float*)d_in[8];  // [128]
    float* out = (float*)d_out;

    const int Nn = in_sizes[0] / 128;
    const int E  = in_sizes[2];

    char* base = (char*)d_ws;
    size_t off = 0;
    auto alloc = [&](size_t bytes) {
        char* p = base + off;
        off = (off + bytes + 255) & ~(size_t)255;
        return p;
    };
    u64_t*  packed = (u64_t*)alloc((size_t)Nn * 8);
    float*  dinv   = (float*)alloc((size_t)Nn * 4);
    int*    offs   = (int*)alloc((size_t)(Nn + 1) * 4);
    int*    bsum   = (int*)alloc(64 * 4);
    int*    bbase  = (int*)alloc(64 * 4);
    int*    rank   = (int*)alloc((size_t)E * 4);
    int2*   edata  = (int2*)alloc((size_t)E * 8);
    ushort_t* xb   = (ushort_t*)alloc((size_t)Nn * 128 * 2);
    ushort_t* h2   = (ushort_t*)alloc((size_t)Nn * 128 * 2);
    ushort_t* W1b  = (ushort_t*)alloc(32768 * 2);
    ushort_t* W2b  = (ushort_t*)alloc(32768 * 2);
    ushort_t* ax   = (ushort_t*)d_out;  // stage ax in d_out (bf16); dead after gemm
    ushort_t* a2   = xb;                // xb dead after agg1 -> reuse for a2
    (void)ws_size; (void)n_in; (void)out_size;

    int gE = (E + 255) / 256;
    int gX = (Nn * 32 + 255) / 256;   // float4 count / 256
    int gW = (Nn + 3) / 4;            // wave per node
    int gG = (Nn + 63) / 64;          // 64 rows per block
    int gQ = 8 * ((Nn + 7) / 8);      // quartered agg: 8-block groups
    int nb = (Nn + 2047) / 2048;      // scan blocks (<= 64)

    hipMemsetAsync(packed, 0, (size_t)Nn * 8, stream);
    k_mega<<<gE + gX + 256, 256, 0, stream>>>(ei, ew, x, W1, W2, packed, rank,
                                              xb, W1b, W2b, E, Nn, gE, gX);
    k_scan_a<<<nb, 256, 0, stream>>>(packed, bsum, Nn);
    k_scan_b<<<1, 64, 0, stream>>>(bsum, bbase, nb, offs, Nn);
    k_scan_c<<<nb, 256, 0, stream>>>(packed, bbase, offs, dinv, Nn);
    k_scatter<<<gE, 256, 0, stream>>>(ei, ew, dinv, offs, rank, edata, E, Nn);
    k_agg1q<<<gQ, 256, 0, stream>>>(xb, offs, edata, dinv, ax, Nn);
    k_gemm_fused<<<gG, 256, 0, stream>>>(ax, W1b, b1v, W2b, h2, Nn);
    k_agg2q<<<gQ, 256, 0, stream>>>(h2, offs, edata, dinv, a2, Nn);
    k_ln<<<gW, 256, 0, stream>>>(a2, b2v, gv, bev, out, Nn);
}

// Round 11
// 321.088 us; speedup vs baseline: 1.1341x; 1.1341x over previous
//
#include <hip/hip_runtime.h>

typedef unsigned short ushort_t;
typedef unsigned long long u64_t;
typedef __attribute__((ext_vector_type(8))) short short8;
typedef __attribute__((ext_vector_type(4))) float float4v;

__device__ inline float b2f(ushort_t u) {
    unsigned x = ((unsigned)u) << 16;
    return __builtin_bit_cast(float, x);
}
__device__ inline ushort_t f2b(float f) {
    unsigned x = __builtin_bit_cast(unsigned, f);
    unsigned r = (x + 0x7fffu + ((x >> 16) & 1u)) >> 16;
    return (ushort_t)r;
}

// Wave-uniform int64-vs-int32 edge_index detection: load the int2 pair at
// edge slot e (valid bytes in BOTH layouts); int64-little-endian => odd word
// is always 0. Any nonzero odd word in the wave => int32.
__device__ inline void load_edge(const int* __restrict__ ei, int e, int E,
                                 int& s, int& d) {
    int ec = min(e, E - 1);
    int2 c64 = ((const int2*)ei)[ec];
    unsigned long long m = __ballot(c64.y != 0);
    if (m != 0ull) {  // int32 layout
        s = ei[ec];
        d = ei[(size_t)E + ec];
    } else {          // int64 layout
        s = c64.x;
        d = ((const int2*)ei)[(size_t)E + ec].x;
    }
}

// ---------------- mega kernel: count (atomic CSR degree+rank) + casts ----------------
// packed[d]: high 32 = edge count, low 32 = sum(w) in 8.24 fixed point.
// One 64-bit atomic per edge; returned old high word = within-segment rank.
// ~45 us, atomic 32B-granule write-through bound (structural floor).

__global__ __launch_bounds__(256) void k_mega(const int* __restrict__ ei,
                                              const float* __restrict__ w,
                                              const float* __restrict__ x,
                                              const float* __restrict__ W1,
                                              const float* __restrict__ W2,
                                              u64_t* packed, int* __restrict__ rank,
                                              ushort_t* __restrict__ xb,
                                              ushort_t* __restrict__ W1b,
                                              ushort_t* __restrict__ W2b,
                                              int E, int Nn, int gE, int gX) {
    int b = blockIdx.x;
    if (b < gE) {
        int e = b * 256 + threadIdx.x;
        int s, d;
        load_edge(ei, e, E, s, d);
        if (e < E) {
            if ((unsigned)s < (unsigned)Nn && (unsigned)d < (unsigned)Nn) {
                unsigned fx = (unsigned)(w[e] * 16777216.0f + 0.5f);
                u64_t old = atomicAdd(packed + d, (1ull << 32) | (u64_t)fx);
                rank[e] = (int)(old >> 32);
            } else {
                rank[e] = -1;
            }
        }
    } else if (b < gE + gX) {
        int i = (b - gE) * 256 + threadIdx.x;  // float4 index
        if (i < Nn * 32) {
            float4v v = ((const float4v*)x)[i];
            ushort4 o;
            o.x = f2b(v[0]); o.y = f2b(v[1]); o.z = f2b(v[2]); o.w = f2b(v[3]);
            ((ushort4*)xb)[i] = o;
        }
    } else {
        int i = (b - gE - gX) * 256 + threadIdx.x;
        if (i < 32768) W1b[i] = f2b(W1[i]);
        else if (i < 65536) W2b[i - 32768] = f2b(W2[i - 32768]);
    }
}

// ---------------- single-block coalesced scan + dinv ----------------
// One block, 1024 threads, 8 elems/thread/chunk (8192/chunk, coalesced),
// LDS block-scan + running base. Replaces the 3-launch scan hierarchy.
// NOTE round-3's 111us single-block scan failed on STRIDED per-thread reads;
// this one is chunk-coalesced.

__global__ __launch_bounds__(1024) void k_scan1(const u64_t* __restrict__ packed,
                                                int* __restrict__ offs,
                                                float* __restrict__ dinv, int Nn) {
    __shared__ int sd[1024];
    __shared__ int base;
    int t = threadIdx.x;
    if (t == 0) base = 0;
    __syncthreads();
    for (int c0 = 0; c0 < Nn; c0 += 8192) {
        int i0 = c0 + t * 8;
        u64_t pk[8];
        int v[8];
        int s = 0;
#pragma unroll
        for (int j = 0; j < 8; ++j) {
            int i = i0 + j;
            pk[j] = (i < Nn) ? packed[i] : 0ull;
            v[j] = (int)(pk[j] >> 32);
            s += v[j];
        }
        sd[t] = s;
        __syncthreads();
        for (int off = 1; off < 1024; off <<= 1) {
            int u = (t >= off) ? sd[t - off] : 0;
            __syncthreads();
            sd[t] += u;
            __syncthreads();
        }
        int pos = base + sd[t] - s;  // base uniform (updated last iter, sync'd)
#pragma unroll
        for (int j = 0; j < 8; ++j) {
            int i = i0 + j;
            if (i < Nn) {
                offs[i] = pos; pos += v[j];
                float deg = 1.0f + (float)(unsigned)(pk[j] & 0xFFFFFFFFull) * (1.0f / 16777216.0f);
                dinv[i] = rsqrtf(deg);  // deg >= 1 (self loop)
            }
        }
        __syncthreads();  // all reads of base done
        if (t == 0) base += sd[1023];
        __syncthreads();
    }
    if (t == 0) offs[Nn] = base;  // grand total
}

// ---------------- scatter (atomic-free): edata[pos] = {src, bits(norm)} ----------------

__global__ void k_scatter(const int* __restrict__ ei, const float* __restrict__ w,
                          const float* __restrict__ dinv,
                          const int* __restrict__ offs,
                          const int* __restrict__ rank,
                          int2* __restrict__ edata, int E, int Nn) {
    int e = blockIdx.x * 256 + threadIdx.x;
    int s, d;
    load_edge(ei, e, E, s, d);  // full wave participates in ballot
    if (e >= E) return;
    int r = rank[e];
    if (r < 0) return;
    int pos = offs[d] + r;
    float nw = dinv[s] * w[e] * dinv[d];
    int2 p;
    p.x = s;
    p.y = __builtin_bit_cast(int, nw);
    edata[pos] = p;
}

// ---------------- split-wave gather core ----------------
// Half p = lane>>5 handles edges i+p, i+p+2, ... Each lane loads ushort4
// (8 B): 32 lanes cover a 256 B row; one VMEM instruction fetches two rows.
// Full-row 256B gathers are the right granularity (round-10 64B slabs wasted
// half of each L2 line). ~40us floor: per-CU miss-concurrency bound.

__device__ inline void agg_edges(const ushort_t* __restrict__ src,
                                 const int2* __restrict__ edata,
                                 int s, int e, int hl, int p, float* a) {
    int i = s;
    for (; i + 7 < e; i += 8) {
#pragma unroll
        for (int j = 0; j < 4; ++j) {
            int idx = i + p + 2 * j;
            int2 ed = edata[idx];
            float nw = __builtin_bit_cast(float, ed.y);
            ushort4 q = ((const ushort4*)(src + (size_t)ed.x * 128))[hl];
            a[0] += b2f(q.x) * nw; a[1] += b2f(q.y) * nw;
            a[2] += b2f(q.z) * nw; a[3] += b2f(q.w) * nw;
        }
    }
    for (; i < e; i += 2) {
        int idx = i + p;
        int ic = min(idx, e - 1);
        int2 ed = edata[ic];
        float nw = (idx < e) ? __builtin_bit_cast(float, ed.y) : 0.f;
        ushort4 q = ((const ushort4*)(src + (size_t)ed.x * 128))[hl];
        a[0] += b2f(q.x) * nw; a[1] += b2f(q.y) * nw;
        a[2] += b2f(q.z) * nw; a[3] += b2f(q.w) * nw;
    }
}

// aggregation 1: ax = A_norm @ x  (bf16 in/out, fp32 acc), wave per node
__global__ __launch_bounds__(256) void k_agg1(const ushort_t* __restrict__ xb,
                                              const int* __restrict__ offs,
                                              const int2* __restrict__ edata,
                                              const float* __restrict__ dinv,
                                              ushort_t* __restrict__ ax, int Nn) {
    int v = (blockIdx.x * blockDim.x + threadIdx.x) >> 6;
    int lane = threadIdx.x & 63;
    if (v >= Nn) return;
    int hl = lane & 31, p = lane >> 5;
    float a[4] = {0.f, 0.f, 0.f, 0.f};
    if (p == 0) {  // self-loop in half 0 only
        float dv = dinv[v];
        float sn = dv * dv;
        ushort4 pq = ((const ushort4*)(xb + (size_t)v * 128))[hl];
        a[0] = b2f(pq.x) * sn; a[1] = b2f(pq.y) * sn;
        a[2] = b2f(pq.z) * sn; a[3] = b2f(pq.w) * sn;
    }
    int s = offs[v], e = offs[v + 1];
    agg_edges(xb, edata, s, e, hl, p, a);
#pragma unroll
    for (int j = 0; j < 4; ++j) a[j] += __shfl_xor(a[j], 32);
    if (p == 0) {
        ushort4 o;
        o.x = f2b(a[0]); o.y = f2b(a[1]); o.z = f2b(a[2]); o.w = f2b(a[3]);
        ((ushort4*)(ax + (size_t)v * 128))[hl] = o;
    }
}

// ---------------- fused GEMM: h2 = relu(ax @ W1^T + b1) @ W2^T ----------------
// Block = 64 rows, 4 waves split the N dimension; W slices + a-frags register-
// prefetched. MFMA 16x16x32 bf16: A row=lane&15,k=quad*8+j; B col=lane&15,
// k=quad*8+j; D col=lane&15,row=quad*4+reg.

__global__ __launch_bounds__(256, 2) void k_gemm_fused(const ushort_t* __restrict__ ax,
                                                       const ushort_t* __restrict__ W1b,
                                                       const float* __restrict__ b1v,
                                                       const ushort_t* __restrict__ W2b,
                                                       ushort_t* __restrict__ h2, int Nn) {
    __shared__ ushort_t tile[64][264];  // 33792 B; stride 264: 16B-aligned rows
    int tid = threadIdx.x, wid = tid >> 6, lane = tid & 63;
    int m = lane & 15, q = lane >> 4;
    int blk = blockIdx.x * 64;

    short8 wf[4][4];  // [nt][kt]
#pragma unroll
    for (int nt = 0; nt < 4; ++nt) {
        const ushort_t* wb = W1b + (size_t)(wid * 64 + nt * 16 + m) * 128 + q * 8;
#pragma unroll
        for (int kt = 0; kt < 4; ++kt) wf[nt][kt] = *(const short8*)(wb + kt * 32);
    }
    short8 af[4][4];  // [mi][kt]
#pragma unroll
    for (int mi = 0; mi < 4; ++mi) {
        int arow = blk + mi * 16 + m;
        bool rv = arow < Nn;
        const ushort_t* ab = ax + (size_t)arow * 128 + q * 8;
#pragma unroll
        for (int kt = 0; kt < 4; ++kt)
            af[mi][kt] = rv ? *(const short8*)(ab + kt * 32) : (short8)0;
    }

    float4v acc1[4][4];
#pragma unroll
    for (int mi = 0; mi < 4; ++mi)
#pragma unroll
        for (int nt = 0; nt < 4; ++nt) acc1[mi][nt] = (float4v){0.f, 0.f, 0.f, 0.f};

#pragma unroll
    for (int kt = 0; kt < 4; ++kt)
#pragma unroll
        for (int mi = 0; mi < 4; ++mi)
#pragma unroll
            for (int nt = 0; nt < 4; ++nt)
                acc1[mi][nt] = __builtin_amdgcn_mfma_f32_16x16x32_bf16(
                    af[mi][kt], wf[nt][kt], acc1[mi][nt], 0, 0, 0);

#pragma unroll
    for (int nt = 0; nt < 4; ++nt) {
        int col = wid * 64 + nt * 16 + m;
        float bb = b1v[col];
#pragma unroll
        for (int mi = 0; mi < 4; ++mi) {
#pragma unroll
            for (int r = 0; r < 4; ++r) {
                float v = acc1[mi][nt][r] + bb;
                v = v > 0.f ? v : 0.f;
                tile[mi * 16 + q * 4 + r][col] = f2b(v);
            }
        }
    }
    __syncthreads();

    short8 w2f[2][8];
#pragma unroll
    for (int n2 = 0; n2 < 2; ++n2) {
        const ushort_t* wb = W2b + (size_t)(wid * 32 + n2 * 16 + m) * 256 + q * 8;
#pragma unroll
        for (int kt = 0; kt < 8; ++kt) w2f[n2][kt] = *(const short8*)(wb + kt * 32);
    }

    float4v acc2[4][2];
#pragma unroll
    for (int mi = 0; mi < 4; ++mi)
#pragma unroll
        for (int n2 = 0; n2 < 2; ++n2) acc2[mi][n2] = (float4v){0.f, 0.f, 0.f, 0.f};

#pragma unroll
    for (int kt = 0; kt < 8; ++kt) {
#pragma unroll
        for (int mi = 0; mi < 4; ++mi) {
            short8 a2 = *(const short8*)&tile[mi * 16 + m][kt * 32 + q * 8];
#pragma unroll
            for (int n2 = 0; n2 < 2; ++n2)
                acc2[mi][n2] = __builtin_amdgcn_mfma_f32_16x16x32_bf16(
                    a2, w2f[n2][kt], acc2[mi][n2], 0, 0, 0);
        }
    }

#pragma unroll
    for (int mi = 0; mi < 4; ++mi) {
#pragma unroll
        for (int n2 = 0; n2 < 2; ++n2) {
            int col = wid * 32 + n2 * 16 + m;
#pragma unroll
            for (int r = 0; r < 4; ++r) {
                int row = blk + mi * 16 + q * 4 + r;
                if (row < Nn) h2[(size_t)row * 128 + col] = f2b(acc2[mi][n2][r]);
            }
        }
    }
}

// ---------------- aggregation 2 + bias + LayerNorm (fp32 out) ----------------

__global__ __launch_bounds__(256) void k_agg2_ln(const ushort_t* __restrict__ h2,
                                                 const int* __restrict__ offs,
                                                 const int2* __restrict__ edata,
                                                 const float* __restrict__ dinv,
                                                 const float* __restrict__ b2v,
                                                 const float* __restrict__ gv,
                                                 const float* __restrict__ bev,
                                                 float* __restrict__ out, int Nn) {
    int v = (blockIdx.x * blockDim.x + threadIdx.x) >> 6;
    int lane = threadIdx.x & 63;
    if (v >= Nn) return;
    int hl = lane & 31, p = lane >> 5;
    float a[4] = {0.f, 0.f, 0.f, 0.f};
    if (p == 0) {
        float dv = dinv[v];
        float sn = dv * dv;
        ushort4 pq = ((const ushort4*)(h2 + (size_t)v * 128))[hl];
        a[0] = b2f(pq.x) * sn; a[1] = b2f(pq.y) * sn;
        a[2] = b2f(pq.z) * sn; a[3] = b2f(pq.w) * sn;
    }
    int s = offs[v], e = offs[v + 1];
    agg_edges(h2, edata, s, e, hl, p, a);
#pragma unroll
    for (int j = 0; j < 4; ++j) a[j] += __shfl_xor(a[j], 32);

    int d0 = hl * 4;
#pragma unroll
    for (int j = 0; j < 4; ++j) a[j] += b2v[d0 + j];

    // every dim held twice (both halves) -> divide by 256
    float ssum = a[0] + a[1] + a[2] + a[3];
    float ssq = a[0] * a[0] + a[1] * a[1] + a[2] * a[2] + a[3] * a[3];
#pragma unroll
    for (int off = 1; off < 64; off <<= 1) {
        ssum += __shfl_xor(ssum, off);
        ssq += __shfl_xor(ssq, off);
    }
    float mu = ssum * (1.0f / 256.0f);
    float var = ssq * (1.0f / 256.0f) - mu * mu;
    float r = rsqrtf(var + 1e-5f);
    if (p == 0) {
        float4v o;
#pragma unroll
        for (int j = 0; j < 4; ++j)
            o[j] = (a[j] - mu) * r * gv[d0 + j] + bev[d0 + j];
        ((float4v*)(out + (size_t)v * 128))[hl] = o;
    }
}

// ---------------- launch ----------------

extern "C" void kernel_launch(void* const* d_in, const int* in_sizes, int n_in,
                              void* d_out, int out_size, void* d_ws, size_t ws_size,
                              hipStream_t stream) {
    const float* x   = (const float*)d_in[0];  // [N,128] f32
    const int*   ei  = (const int*)d_in[1];    // [2,E] int32/int64 (detected)
    const float* ew  = (const float*)d_in[2];  // [E] f32
    const float* W1  = (const float*)d_in[3];  // [256,128] f32
    const float* b1v = (const float*)d_in[4];  // [256]
    const float* W2  = (const float*)d_in[5];  // [128,256]
    const float* b2v = (const float*)d_in[6];  // [128]
    const float* gv  = (const float*)d_in[7];  // [128]
    const float* bev = (const float*)d_in[8];  // [128]
    float* out = (float*)d_out;

    const int Nn = in_sizes[0] / 128;
    const int E  = in_sizes[2];

    char* base = (char*)d_ws;
    size_t off = 0;
    auto alloc = [&](size_t bytes) {
        char* p = base + off;
        off = (off + bytes + 255) & ~(size_t)255;
        return p;
    };
    u64_t*  packed = (u64_t*)alloc((size_t)Nn * 8);
    float*  dinv   = (float*)alloc((size_t)Nn * 4);
    int*    offs   = (int*)alloc((size_t)(Nn + 1) * 4);
    int*    rank   = (int*)alloc((size_t)E * 4);
    int2*   edata  = (int2*)alloc((size_t)E * 8);
    ushort_t* xb   = (ushort_t*)alloc((size_t)Nn * 128 * 2);
    ushort_t* h2   = (ushort_t*)alloc((size_t)Nn * 128 * 2);
    ushort_t* W1b  = (ushort_t*)alloc(32768 * 2);
    ushort_t* W2b  = (ushort_t*)alloc(32768 * 2);
    ushort_t* ax   = (ushort_t*)d_out;  // stage ax in d_out (bf16); dead before final write
    (void)ws_size; (void)n_in; (void)out_size;

    int gE = (E + 255) / 256;
    int gX = (Nn * 32 + 255) / 256;   // float4 count / 256
    int gW = (Nn + 3) / 4;            // wave per node
    int gG = (Nn + 63) / 64;          // 64 rows per block

    hipMemsetAsync(packed, 0, (size_t)Nn * 8, stream);
    k_mega<<<gE + gX + 256, 256, 0, stream>>>(ei, ew, x, W1, W2, packed, rank,
                                              xb, W1b, W2b, E, Nn, gE, gX);
    k_scan1<<<1, 1024, 0, stream>>>(packed, offs, dinv, Nn);
    k_scatter<<<gE, 256, 0, stream>>>(ei, ew, dinv, offs, rank, edata, E, Nn);
    k_agg1<<<gW, 256, 0, stream>>>(xb, offs, edata, dinv, ax, Nn);
    k_gemm_fused<<<gG, 256, 0, stream>>>(ax, W1b, b1v, W2b, h2, Nn);
    k_agg2_ln<<<gW, 256, 0, stream>>>(h2, offs, edata, dinv, b2v, gv, bev, out, Nn);
}